// Round 20
// baseline (493.956 us; speedup 1.0000x reference)
//
#include <hip/hip_runtime.h>

namespace {

constexpr int Bn = 32, Cn = 8, Hn = 512, In = 512;
constexpr size_t HI = (size_t)Hn * In;     // 262144
constexpr float SC = 1.0f / 5000.0f;

using s16x8 = __attribute__((ext_vector_type(8))) short;
using u16x8 = __attribute__((ext_vector_type(8))) unsigned short;
using f32x4 = __attribute__((ext_vector_type(4))) float;

__device__ __forceinline__ float actf(float x) {
    return fminf(1.0f, fmaxf(-1.0f, x));   // hardtanh
}

__device__ __forceinline__ unsigned short f2bf(float f) {   // RNE f32->bf16
    unsigned u = __builtin_bit_cast(unsigned, f);
    u += 0x7FFFu + ((u >> 16) & 1u);
    return (unsigned short)(u >> 16);
}
__device__ __forceinline__ float bf2f(unsigned short h) {
    return __builtin_bit_cast(float, (unsigned)h << 16);
}

__device__ __forceinline__ void async16(const void* g, void* l) {
    __builtin_amdgcn_global_load_lds(
        (const __attribute__((address_space(1))) unsigned*)g,
        (__attribute__((address_space(3))) unsigned*)l, 16, 0, 0);
}

#define CFENCE asm volatile("" ::: "memory")
#define BAR do { CFENCE; __builtin_amdgcn_s_barrier(); CFENCE; } while (0)

// ---------------------------------------------------------------------------
// r20: 8-phase 256x256 kernel with ds_read HOIST — each intra-K-tile phase's
// ds_reads issue inside the PREVIOUS phase's MFMA window (overlap MFMA exec),
// instead of serially between barriers. Current-phase operands were issued a
// phase earlier -> lgkmcnt before QMM already satisfied.
// Hazards (audited): hoisted rdB2(daB,2) reads complete by P2-QMM, daB first
// overwritten at P3-stage (after P2 end-BAR). Hoisted rdA4(daA,4) consumed
// P3/P4, daA overwritten at P5-stage. Cross-K-tile rds stay behind the entry
// vmcnt+BAR. Stage slots / vmcnt(4)@P4,P8 / barrier count unchanged (r18).
// EPI 0: G1 bf16(act(acc));  1: G2 dual;  2: G3 act+bias.
// ---------------------------------------------------------------------------
template<int EPI, bool PCOL, bool TRI>
__global__ __launch_bounds__(512, 2) void gemm256_8p(
    const unsigned short* __restrict__ A,
    const unsigned short* __restrict__ Bt,
    const float* __restrict__ bias,
    const float* __restrict__ zrow,
    unsigned short* __restrict__ out0,
    unsigned short* __restrict__ out1,
    size_t sB, size_t sC)
{
    __shared__ __align__(16) char lds[131072];
    char* daA = lds;
    char* dbA = lds + 32768;
    char* daB = lds + 65536;
    char* dbB = lds + 98304;

    const int tid = threadIdx.x;
    const int lane = tid & 63, l15 = lane & 15, kq = lane >> 4;
    const int wid = tid >> 6, wm = wid >> 2, wn = wid & 3;

    const int bid = blockIdx.x;
    int rt, ct; size_t zb;
    if (PCOL) {   // G1: p=z (XCD-group), q=(rt,ct); long (rt=1) blocks first
        const int p = ((bid >> 5) << 3) | (bid & 7);
        const int q = (bid >> 3) & 3;
        zb = (size_t)p; rt = 1 - (q >> 1); ct = q & 1;
    } else {      // G2/G3: p=row-tile, q=ct
        const int p = ((bid >> 4) << 3) | (bid & 7);
        const int q = (bid >> 3) & 1;
        zb = 0; rt = p; ct = q;
    }

    const char* Ab = (const char*)A + (size_t)rt * 256 * 1024;
    const char* Bb = (const char*)(Bt + zb * sB) + (size_t)ct * 256 * 1024;

    const int nkt = TRI ? (rt + 1) * 4 : 8;   // 64-K tiles (even)
    const int nit = nkt >> 1;

    const int srow8 = tid >> 3;                       // 0..63
    const int csw   = ((tid & 7) ^ (srow8 & 7)) << 4;

    auto stageH = [&](const char* src, int kt, int half, char* dstTile) {
        const char* s = src + ((size_t)half * 128 + srow8) * 1024 + kt * 128 + csw;
        char* d = dstTile + half * 16384 + tid * 16;
        async16(s,             d);
        async16(s + 64 * 1024, d + 8192);
    };

    const int kx0 = ((kq    ) ^ (l15 & 7)) << 4;
    const int kx1 = ((kq + 4) ^ (l15 & 7)) << 4;

    auto rdA4 = [&](const char* tile, int mlo, s16x8 a[2][4]) {
        #pragma unroll
        for (int i = 0; i < 4; ++i) {
            const int row = wm * 128 + (mlo + i) * 16 + l15;
            a[0][i] = *(const s16x8*)(tile + row * 128 + kx0);
            a[1][i] = *(const s16x8*)(tile + row * 128 + kx1);
        }
    };
    auto rdB2 = [&](const char* tile, int nlo, s16x8 b[2][2]) {
        #pragma unroll
        for (int j = 0; j < 2; ++j) {
            const int row = wn * 64 + (nlo + j) * 16 + l15;
            b[0][j] = *(const s16x8*)(tile + row * 128 + kx0);
            b[1][j] = *(const s16x8*)(tile + row * 128 + kx1);
        }
    };

    f32x4 acc[8][4] = {};

    auto QMM = [&](s16x8 a[2][4], s16x8 b[2][2], int mlo, int nlo) {
        __builtin_amdgcn_s_setprio(1);
        #pragma unroll
        for (int kk = 0; kk < 2; ++kk)
            #pragma unroll
            for (int i = 0; i < 4; ++i)
                #pragma unroll
                for (int j = 0; j < 2; ++j)
                    acc[mlo + i][nlo + j] = __builtin_amdgcn_mfma_f32_16x16x32_bf16(
                        a[kk][i], b[kk][j], acc[mlo + i][nlo + j], 0, 0, 0);
        __builtin_amdgcn_s_setprio(0);
    };

    // prologue
    stageH(Bb, 0, 0, daB); stageH(Bb, 0, 1, daB);
    stageH(Ab, 0, 0, daA); stageH(Ab, 0, 1, daA);
    stageH(Bb, 1, 0, dbB); stageH(Bb, 1, 1, dbB);
    asm volatile("s_waitcnt vmcnt(4)" ::: "memory");
    BAR;

    #pragma unroll 1
    for (int t = 0; t < nit; ++t) {
        const int j = 2 * t;
        const bool more = (t + 1 < nit);
        s16x8 a03[2][4], a47[2][4], b01[2][2], b23[2][2];

        // ======== K-tile j (da buffers) ========
        rdA4(daA, 0, a03); rdB2(daB, 0, b01);   // P1 ops (after entry BAR)
        stageH(Ab, j + 1, 0, dbA);              // P1 stage
        BAR;
        rdB2(daB, 2, b23);                      // P2 ops, hoisted into P1 MFMA window
        QMM(a03, b01, 0, 0);
        BAR;
        stageH(Ab, j + 1, 1, dbA);              // P2 stage
        BAR;
        rdA4(daA, 4, a47);                      // P3 ops, hoisted into P2 MFMA window
        QMM(a03, b23, 0, 2);
        BAR;
        if (more) stageH(Bb, j + 2, 0, daB);    // P3 stage (b01/b23 already in regs)
        BAR;
        QMM(a47, b23, 4, 2);
        BAR;
        if (more) stageH(Bb, j + 2, 1, daB);    // P4 stage
        BAR;
        QMM(a47, b01, 4, 0);
        if (more) asm volatile("s_waitcnt vmcnt(4)" ::: "memory");
        else      asm volatile("s_waitcnt vmcnt(0)" ::: "memory");
        BAR;

        // ======== K-tile j+1 (db buffers) ========
        rdA4(dbA, 0, a03); rdB2(dbB, 0, b01);   // P5 ops (after vmcnt+BAR)
        if (more) stageH(Ab, j + 2, 0, daA);    // P5 stage
        BAR;
        rdB2(dbB, 2, b23);                      // P6 ops, hoisted
        QMM(a03, b01, 0, 0);
        BAR;
        if (more) stageH(Ab, j + 2, 1, daA);    // P6 stage
        BAR;
        rdA4(dbA, 4, a47);                      // P7 ops, hoisted
        QMM(a03, b23, 0, 2);
        BAR;
        if (more) stageH(Bb, j + 3, 0, dbB);    // P7 stage
        BAR;
        QMM(a47, b23, 4, 2);
        BAR;
        if (more) stageH(Bb, j + 3, 1, dbB);    // P8 stage
        BAR;
        QMM(a47, b01, 4, 0);
        if (more) { asm volatile("s_waitcnt vmcnt(4)" ::: "memory"); BAR; }
        else BAR;
    }

    // ---- epilogue: C/D map col=lane&15, row=(lane>>4)*4+j ----
    const int rbase = rt * 256 + wm * 128 + kq * 4;
    const int cb    = ct * 256 + wn * 64 + l15;
    #pragma unroll
    for (int mi = 0; mi < 8; ++mi) {
        #pragma unroll
        for (int n = 0; n < 4; ++n) {
            const int c = cb + n * 16;
            const float bs = (EPI == 0) ? 0.0f : bias[c];
            #pragma unroll
            for (int jj = 0; jj < 4; ++jj) {
                const size_t r = (size_t)rbase + mi * 16 + jj;
                const size_t idx = zb * sC + r * 512 + c;
                float v = acc[mi][n][jj];
                if (EPI == 0) {
                    out0[idx] = f2bf(actf(v));
                } else if (EPI == 1) {
                    float tp = actf(v + bs);
                    out0[idx] = f2bf(tp);
                    out1[idx] = f2bf(actf(zrow[r & 511] * tp));
                } else {
                    out0[idx] = f2bf(actf(v + bs));
                }
            }
        }
    }
}

// ---------------------------------------------------------------------------
// r16 128x128 kernel for fc1/fc2 (EPI 3 = relu+bias bf16, 4 = fp32+bias)
// ---------------------------------------------------------------------------
template<int EPI>
__global__ __launch_bounds__(256, 3) void mfma_gemm128(
    const unsigned short* __restrict__ A,
    const unsigned short* __restrict__ Bt,
    const float* __restrict__ bias,
    unsigned short* __restrict__ out0,
    float* __restrict__ outf)
{
    __shared__ __align__(16) char lds[2][16384];

    const int tid  = threadIdx.x;
    const int wid  = tid >> 6, lane = tid & 63;
    const int wr   = wid >> 1, wc = wid & 1;
    const int l15  = lane & 15, kq = lane >> 4;

    const int bid = blockIdx.x;
    const int p = ((bid >> 5) << 3) | (bid & 7);
    const int q = (bid >> 3) & 3;
    const int rt = p, ct = q;

    const char* Ab = (const char*)A + (size_t)rt * 131072;
    const char* Bb = (const char*)Bt + (size_t)ct * 131072;

    f32x4 acc[4][4] = {};

    const int o0  = tid * 16;
    const int r0s = o0 >> 6;
    const int c0s = o0 & 63;
    const int csw = c0s ^ (((r0s >> 1) & 3) << 4);

    auto stage = [&](char* buf, int k0b) {
        async16(Ab + (size_t)r0s * 1024 + k0b + csw,        buf + wid * 1024);
        async16(Ab + (size_t)(64 + r0s) * 1024 + k0b + csw, buf + 4096 + wid * 1024);
        async16(Bb + (size_t)r0s * 1024 + k0b + csw,        buf + 8192 + wid * 1024);
        async16(Bb + (size_t)(64 + r0s) * 1024 + k0b + csw, buf + 12288 + wid * 1024);
    };
    auto compute = [&](const char* buf) {
        s16x8 a[4], b[4];
        const int kx = kq * 16 ^ (((l15 >> 1) & 3) << 4);
        const int ar = wr * 64 + l15;
        const int br = wc * 64 + l15;
        #pragma unroll
        for (int m = 0; m < 4; ++m)
            a[m] = *(const s16x8*)(buf + (size_t)(ar + m * 16) * 64 + kx);
        #pragma unroll
        for (int n = 0; n < 4; ++n)
            b[n] = *(const s16x8*)(buf + 8192 + (size_t)(br + n * 16) * 64 + kx);
        #pragma unroll
        for (int m = 0; m < 4; ++m)
            #pragma unroll
            for (int n = 0; n < 4; ++n)
                acc[m][n] = __builtin_amdgcn_mfma_f32_16x16x32_bf16(a[m], b[n], acc[m][n], 0, 0, 0);
    };

    stage(lds[0], 0);
    stage(lds[1], 64);

    #pragma unroll 1
    for (int ks = 0; ks < 16; ks += 2) {
        const bool more = (ks + 2 < 16);
        asm volatile("s_waitcnt vmcnt(4)" ::: "memory");
        BAR;
        compute(lds[0]);
        BAR;
        if (more) stage(lds[0], (ks + 2) * 64);
        if (more) asm volatile("s_waitcnt vmcnt(4)" ::: "memory");
        else      asm volatile("s_waitcnt vmcnt(0)" ::: "memory");
        BAR;
        compute(lds[1]);
        BAR;
        if (more) stage(lds[1], (ks + 3) * 64);
    }

    const int cb = ct * 128 + wc * 64 + l15;
    const int rb = rt * 128 + wr * 64 + (kq << 2);
    #pragma unroll
    for (int m = 0; m < 4; ++m)
        #pragma unroll
        for (int n = 0; n < 4; ++n) {
            const int c = cb + n * 16;
            #pragma unroll
            for (int j = 0; j < 4; ++j) {
                const int r = rb + m * 16 + j;
                const size_t idx = (size_t)r * 512 + c;
                float v = acc[m][n][j] + bias[c];
                if (EPI == 3) out0[idx] = f2bf(fmaxf(v, 0.0f));
                else          outf[idx] = v;
            }
        }
}

// comb[b] = bf16( x0[b]/5000 + sum_c tp[b,c] + sum_c tz[b,c] )  — 16B/lane
__global__ __launch_bounds__(256) void reduce_both(
    const unsigned short* __restrict__ tp,
    const unsigned short* __restrict__ tz,
    const float* __restrict__ x0,
    unsigned short* __restrict__ comb)
{
    size_t idx = (size_t)blockIdx.x * 256 + threadIdx.x;   // ushort8 slot
    size_t b = idx >> 15;                                  // / (HI/8)
    size_t p = (idx & 32767) * 8;
    float4 xa = *(const float4*)&x0[(b * Cn) * HI + p];
    float4 xb = *(const float4*)&x0[(b * Cn) * HI + p + 4];
    float s[8] = { xa.x * SC, xa.y * SC, xa.z * SC, xa.w * SC,
                   xb.x * SC, xb.y * SC, xb.z * SC, xb.w * SC };
    #pragma unroll
    for (int c = 0; c < Cn; ++c) {
        size_t q = (b * Cn + c) * HI + p;
        u16x8 a = *(const u16x8*)&tp[q];
        u16x8 d = *(const u16x8*)&tz[q];
        #pragma unroll
        for (int j = 0; j < 8; ++j) s[j] += bf2f(a[j]) + bf2f(d[j]);
    }
    u16x8 o;
    #pragma unroll
    for (int j = 0; j < 8; ++j) o[j] = f2bf(s[j]);
    *(u16x8*)&comb[b * HI + p] = o;
}

// xst[bc][i][k] = bf16( x[bc][k][i] * act(mask[k][i]) / 5000 )
__global__ __launch_bounds__(256) void transpose_mask(
    const float* __restrict__ x, const float* __restrict__ mask,
    unsigned short* __restrict__ xst)
{
    __shared__ float t[64][65];
    const int bc = blockIdx.z;
    const int i0 = blockIdx.x * 64, k0 = blockIdx.y * 64;
    const int r16 = threadIdx.x >> 4;          // 0..15
    const int c4  = (threadIdx.x & 15) * 4;    // 0..60
    const float* xp = x + (size_t)bc * HI;
    #pragma unroll
    for (int ps = 0; ps < 4; ++ps) {
        const int kl = ps * 16 + r16;
        const size_t g = (size_t)(k0 + kl) * In + i0 + c4;
        float4 xv = *(const float4*)&xp[g];
        float4 mv = *(const float4*)&mask[g];
        t[kl][c4 + 0] = xv.x * (actf(mv.x) * SC);
        t[kl][c4 + 1] = xv.y * (actf(mv.y) * SC);
        t[kl][c4 + 2] = xv.z * (actf(mv.z) * SC);
        t[kl][c4 + 3] = xv.w * (actf(mv.w) * SC);
    }
    __syncthreads();
    unsigned short* op = xst + (size_t)bc * HI;
    #pragma unroll
    for (int ps = 0; ps < 4; ++ps) {
        const int il = ps * 16 + r16;
        ushort4 o;
        o.x = f2bf(t[c4 + 0][il]);
        o.y = f2bf(t[c4 + 1][il]);
        o.z = f2bf(t[c4 + 2][il]);
        o.w = f2bf(t[c4 + 3][il]);
        *(ushort4*)&op[(size_t)(i0 + il) * Hn + k0 + c4] = o;
    }
}

__global__ __launch_bounds__(256) void prep_wpe_bf(
    const float* __restrict__ Wp, const float* __restrict__ Wpd,
    unsigned short* __restrict__ o)
{
    int idx = blockIdx.x * 256 + threadIdx.x;
    int i = idx >> 9, j = idx & 511;
    o[idx] = f2bf(Wp[idx] + (i == j ? Wpd[i] : 0.0f));
}

// all four weight conversions in one launch (float4 in, ushort4 out)
__global__ __launch_bounds__(256) void conv_bf4(
    const float* __restrict__ s0, const float* __restrict__ s1,
    const float* __restrict__ s2, const float* __restrict__ s3,
    unsigned short* __restrict__ d0, unsigned short* __restrict__ d1,
    unsigned short* __restrict__ d2, unsigned short* __restrict__ d3)
{
    const int m = blockIdx.x >> 8;                       // 256 blocks/matrix
    const int idx = ((blockIdx.x & 255) * 256 + threadIdx.x);  // float4 idx
    const float* s = (m == 0) ? s0 : (m == 1) ? s1 : (m == 2) ? s2 : s3;
    unsigned short* d = (m == 0) ? d0 : (m == 1) ? d1 : (m == 2) ? d2 : d3;
    float4 v = ((const float4*)s)[idx];
    ushort4 o;
    o.x = f2bf(v.x); o.y = f2bf(v.y); o.z = f2bf(v.z); o.w = f2bf(v.w);
    ((ushort4*)d)[idx] = o;
}

__global__ __launch_bounds__(64) void rowsum(
    const float* __restrict__ W, float* __restrict__ zr)
{
    int h = blockIdx.x, l = threadIdx.x;
    float s = 0.0f;
    for (int k = l; k < Hn; k += 64) s += W[h * Hn + k];
    #pragma unroll
    for (int off = 32; off; off >>= 1) s += __shfl_down(s, off, 64);
    if (!l) zr[h] = s;
}

} // namespace

extern "C" void kernel_launch(void* const* d_in, const int* in_sizes, int n_in,
                              void* d_out, int out_size, void* d_ws, size_t ws_size,
                              hipStream_t stream)
{
    const float* input  = (const float*)d_in[0];
    const float* p_mask = (const float*)d_in[1];
    const float* Wp     = (const float*)d_in[2];
    const float* Wpd    = (const float*)d_in[3];
    const float* Wzp    = (const float*)d_in[4];
    const float* plw    = (const float*)d_in[5];
    const float* plb    = (const float*)d_in[6];
    const float* zlw    = (const float*)d_in[7];
    const float* zlb    = (const float*)d_in[8];
    const float* f1w    = (const float*)d_in[9];
    const float* f1b    = (const float*)d_in[10];
    const float* f2w    = (const float*)d_in[11];
    const float* f2b    = (const float*)d_in[12];

    constexpr size_t WB = 512 * 512 * 2;   // one bf16 weight matrix
    char* w = (char*)d_ws;
    auto alloc = [&](size_t bytes) { char* p = w; w += (bytes + 255) & ~255ull; return p; };

    unsigned short* Wpeb  = (unsigned short*)alloc(WB);
    unsigned short* plwb  = (unsigned short*)alloc(WB);
    unsigned short* zlwb  = (unsigned short*)alloc(WB);
    unsigned short* f1wb  = (unsigned short*)alloc(WB);
    unsigned short* f2wb  = (unsigned short*)alloc(WB);
    float*          zrw   = (float*)alloc(512 * 4);
    unsigned short* combb = (unsigned short*)alloc((size_t)Bn * HI * 2);
    unsigned short* out1  = (unsigned short*)alloc((size_t)Bn * HI * 2);

    size_t fixedB = (size_t)(w - (char*)d_ws);
    int chunk = 32;
    while (chunk > 1 &&
           fixedB + 4ull * (size_t)chunk * Cn * HI * 2 + 4096 > ws_size)
        chunk >>= 1;
    const size_t CB = (size_t)chunk * Cn * HI * 2;
    unsigned short* xst   = (unsigned short*)alloc(CB);   // reused for tz
    unsigned short* tpact = (unsigned short*)alloc(CB);
    unsigned short* tpb   = (unsigned short*)alloc(CB);
    unsigned short* tzin  = (unsigned short*)alloc(CB);
    unsigned short* tzb   = xst;

    prep_wpe_bf<<<512 * 512 / 256, 256, 0, stream>>>(Wp, Wpd, Wpeb);
    conv_bf4<<<1024, 256, 0, stream>>>(plw, zlw, f1w, f2w, plwb, zlwb, f1wb, f2wb);
    rowsum<<<512, 64, 0, stream>>>(Wzp, zrw);

    for (int b0 = 0; b0 < Bn; b0 += chunk) {
        const int nc = chunk * Cn;
        const float* inp_c = input + (size_t)b0 * Cn * HI;

        // xst = bf16(x^T * act(mask)/5000)
        transpose_mask<<<dim3(8, 8, nc), 256, 0, stream>>>(inp_c, p_mask, xst);
        // G1: tpact[z] = act(Wpe @ xst[z]^T)  — 8-phase 256², PCOL + TRI
        gemm256_8p<0, true, true><<<nc * 4, 512, 0, stream>>>(
            Wpeb, xst, nullptr, nullptr, tpact, nullptr, HI, HI);
        // G2: tp = act(tpact @ plw^T + plb); tzin = act(zrow*tp)
        gemm256_8p<1, false, false><<<nc * 4, 512, 0, stream>>>(
            tpact, plwb, plb, zrw, tpb, tzin, 0, 0);
        // G3: tz = act(tzin @ zlw^T + zlb)
        gemm256_8p<2, false, false><<<nc * 4, 512, 0, stream>>>(
            tzin, zlwb, zlb, nullptr, tzb, nullptr, 0, 0);
        // comb = x0/5000 + sum_c tp + sum_c tz
        reduce_both<<<chunk * 128, 256, 0, stream>>>(
            tpb, tzb, inp_c, combb + (size_t)b0 * HI);
    }

    // fc1: out1 = relu(combb @ f1w^T + f1b)
    mfma_gemm128<3><<<512, 256, 0, stream>>>(combb, f1wb, f1b, out1, nullptr);
    // fc2: out = out1 @ f2w^T + f2b   (fp32)
    mfma_gemm128<4><<<512, 256, 0, stream>>>(out1, f2wb, f2b, nullptr, (float*)d_out);
}

// Round 21
// 488.624 us; speedup vs baseline: 1.0109x; 1.0109x over previous
//
#include <hip/hip_runtime.h>

namespace {

constexpr int Bn = 32, Cn = 8, Hn = 512, In = 512;
constexpr size_t HI = (size_t)Hn * In;     // 262144
constexpr float SC = 1.0f / 5000.0f;

using s16x8 = __attribute__((ext_vector_type(8))) short;
using u16x8 = __attribute__((ext_vector_type(8))) unsigned short;
using f32x4 = __attribute__((ext_vector_type(4))) float;

__device__ __forceinline__ float actf(float x) {
    return fminf(1.0f, fmaxf(-1.0f, x));   // hardtanh
}

__device__ __forceinline__ unsigned short f2bf(float f) {   // RNE f32->bf16
    unsigned u = __builtin_bit_cast(unsigned, f);
    u += 0x7FFFu + ((u >> 16) & 1u);
    return (unsigned short)(u >> 16);
}
__device__ __forceinline__ float bf2f(unsigned short h) {
    return __builtin_bit_cast(float, (unsigned)h << 16);
}

__device__ __forceinline__ void async16(const void* g, void* l) {
    __builtin_amdgcn_global_load_lds(
        (const __attribute__((address_space(1))) unsigned*)g,
        (__attribute__((address_space(3))) unsigned*)l, 16, 0, 0);
}

#define CFENCE asm volatile("" ::: "memory")
#define BAR do { CFENCE; __builtin_amdgcn_s_barrier(); CFENCE; } while (0)

// ---------------------------------------------------------------------------
// Champion (r19): 8-phase 256x256 template. BK=64, 8 waves (512 thr),
// per-wave 128x64 (acc[8][4]). LDS 128KB dbuf x (A|B), row-major [256][128B],
// XOR involution ((t&7)^(row&7))<<4 on both sides (coalescing preserved,
// ds_read conflict-free). Counted vmcnt(4) only at P4/P8 (prefetch never
// drained mid-loop); setprio around MFMA clusters; XCD-colocating decode;
// TRI for lower-triangular Wp_eff. G1 long-blocks-first.
// EPI 0: G1 bf16(act(acc));  1: G2 dual;  2: G3 act+bias.
// ---------------------------------------------------------------------------
template<int EPI, bool PCOL, bool TRI>
__global__ __launch_bounds__(512, 2) void gemm256_8p(
    const unsigned short* __restrict__ A,
    const unsigned short* __restrict__ Bt,
    const float* __restrict__ bias,
    const float* __restrict__ zrow,
    unsigned short* __restrict__ out0,
    unsigned short* __restrict__ out1,
    size_t sB, size_t sC)
{
    __shared__ __align__(16) char lds[131072];
    char* daA = lds;
    char* dbA = lds + 32768;
    char* daB = lds + 65536;
    char* dbB = lds + 98304;

    const int tid = threadIdx.x;
    const int lane = tid & 63, l15 = lane & 15, kq = lane >> 4;
    const int wid = tid >> 6, wm = wid >> 2, wn = wid & 3;

    const int bid = blockIdx.x;
    int rt, ct; size_t zb;
    if (PCOL) {   // G1: p=z (XCD-group), q=(rt,ct); long (rt=1) blocks first
        const int p = ((bid >> 5) << 3) | (bid & 7);
        const int q = (bid >> 3) & 3;
        zb = (size_t)p; rt = 1 - (q >> 1); ct = q & 1;
    } else {      // G2/G3: p=row-tile, q=ct
        const int p = ((bid >> 4) << 3) | (bid & 7);
        const int q = (bid >> 3) & 1;
        zb = 0; rt = p; ct = q;
    }

    const char* Ab = (const char*)A + (size_t)rt * 256 * 1024;
    const char* Bb = (const char*)(Bt + zb * sB) + (size_t)ct * 256 * 1024;

    const int nkt = TRI ? (rt + 1) * 4 : 8;   // 64-K tiles (even)
    const int nit = nkt >> 1;

    const int srow8 = tid >> 3;                       // 0..63
    const int csw   = ((tid & 7) ^ (srow8 & 7)) << 4;

    auto stageH = [&](const char* src, int kt, int half, char* dstTile) {
        const char* s = src + ((size_t)half * 128 + srow8) * 1024 + kt * 128 + csw;
        char* d = dstTile + half * 16384 + tid * 16;
        async16(s,             d);
        async16(s + 64 * 1024, d + 8192);
    };

    const int kx0 = ((kq    ) ^ (l15 & 7)) << 4;
    const int kx1 = ((kq + 4) ^ (l15 & 7)) << 4;

    auto rdA4 = [&](const char* tile, int mlo, s16x8 a[2][4]) {
        #pragma unroll
        for (int i = 0; i < 4; ++i) {
            const int row = wm * 128 + (mlo + i) * 16 + l15;
            a[0][i] = *(const s16x8*)(tile + row * 128 + kx0);
            a[1][i] = *(const s16x8*)(tile + row * 128 + kx1);
        }
    };
    auto rdB2 = [&](const char* tile, int nlo, s16x8 b[2][2]) {
        #pragma unroll
        for (int j = 0; j < 2; ++j) {
            const int row = wn * 64 + (nlo + j) * 16 + l15;
            b[0][j] = *(const s16x8*)(tile + row * 128 + kx0);
            b[1][j] = *(const s16x8*)(tile + row * 128 + kx1);
        }
    };

    f32x4 acc[8][4] = {};

    auto QMM = [&](s16x8 a[2][4], s16x8 b[2][2], int mlo, int nlo) {
        __builtin_amdgcn_s_setprio(1);
        #pragma unroll
        for (int kk = 0; kk < 2; ++kk)
            #pragma unroll
            for (int i = 0; i < 4; ++i)
                #pragma unroll
                for (int j = 0; j < 2; ++j)
                    acc[mlo + i][nlo + j] = __builtin_amdgcn_mfma_f32_16x16x32_bf16(
                        a[kk][i], b[kk][j], acc[mlo + i][nlo + j], 0, 0, 0);
        __builtin_amdgcn_s_setprio(0);
    };

    // prologue
    stageH(Bb, 0, 0, daB); stageH(Bb, 0, 1, daB);
    stageH(Ab, 0, 0, daA); stageH(Ab, 0, 1, daA);
    stageH(Bb, 1, 0, dbB); stageH(Bb, 1, 1, dbB);
    asm volatile("s_waitcnt vmcnt(4)" ::: "memory");
    BAR;

    #pragma unroll 1
    for (int t = 0; t < nit; ++t) {
        const int j = 2 * t;
        const bool more = (t + 1 < nit);
        s16x8 a03[2][4], a47[2][4], b01[2][2], b23[2][2];

        // ======== K-tile j (dbuf0) ========
        rdA4(daA, 0, a03); rdB2(daB, 0, b01);
        stageH(Ab, j + 1, 0, dbA);
        BAR; QMM(a03, b01, 0, 0); BAR;
        rdB2(daB, 2, b23);
        stageH(Ab, j + 1, 1, dbA);
        BAR; QMM(a03, b23, 0, 2); BAR;
        rdA4(daA, 4, a47);
        if (more) stageH(Bb, j + 2, 0, daB);
        BAR; QMM(a47, b23, 4, 2); BAR;
        if (more) stageH(Bb, j + 2, 1, daB);
        BAR; QMM(a47, b01, 4, 0);
        if (more) asm volatile("s_waitcnt vmcnt(4)" ::: "memory");
        else      asm volatile("s_waitcnt vmcnt(0)" ::: "memory");
        BAR;

        // ======== K-tile j+1 (dbuf1) ========
        rdA4(dbA, 0, a03); rdB2(dbB, 0, b01);
        if (more) stageH(Ab, j + 2, 0, daA);
        BAR; QMM(a03, b01, 0, 0); BAR;
        rdB2(dbB, 2, b23);
        if (more) stageH(Ab, j + 2, 1, daA);
        BAR; QMM(a03, b23, 0, 2); BAR;
        rdA4(dbA, 4, a47);
        if (more) stageH(Bb, j + 3, 0, dbB);
        BAR; QMM(a47, b23, 4, 2); BAR;
        if (more) stageH(Bb, j + 3, 1, dbB);
        BAR; QMM(a47, b01, 4, 0);
        if (more) { asm volatile("s_waitcnt vmcnt(4)" ::: "memory"); BAR; }
        else BAR;
    }

    // ---- epilogue: C/D map col=lane&15, row=(lane>>4)*4+j ----
    const int rbase = rt * 256 + wm * 128 + kq * 4;
    const int cb    = ct * 256 + wn * 64 + l15;
    #pragma unroll
    for (int mi = 0; mi < 8; ++mi) {
        #pragma unroll
        for (int n = 0; n < 4; ++n) {
            const int c = cb + n * 16;
            const float bs = (EPI == 0) ? 0.0f : bias[c];
            #pragma unroll
            for (int jj = 0; jj < 4; ++jj) {
                const size_t r = (size_t)rbase + mi * 16 + jj;
                const size_t idx = zb * sC + r * 512 + c;
                float v = acc[mi][n][jj];
                if (EPI == 0) {
                    out0[idx] = f2bf(actf(v));
                } else if (EPI == 1) {
                    float tp = actf(v + bs);
                    out0[idx] = f2bf(tp);
                    out1[idx] = f2bf(actf(zrow[r & 511] * tp));
                } else {
                    out0[idx] = f2bf(actf(v + bs));
                }
            }
        }
    }
}

// ---------------------------------------------------------------------------
// r16 128x128 kernel for fc1/fc2 (EPI 3 = relu+bias bf16, 4 = fp32+bias)
// ---------------------------------------------------------------------------
template<int EPI>
__global__ __launch_bounds__(256, 3) void mfma_gemm128(
    const unsigned short* __restrict__ A,
    const unsigned short* __restrict__ Bt,
    const float* __restrict__ bias,
    unsigned short* __restrict__ out0,
    float* __restrict__ outf)
{
    __shared__ __align__(16) char lds[2][16384];

    const int tid  = threadIdx.x;
    const int wid  = tid >> 6, lane = tid & 63;
    const int wr   = wid >> 1, wc = wid & 1;
    const int l15  = lane & 15, kq = lane >> 4;

    const int bid = blockIdx.x;
    const int p = ((bid >> 5) << 3) | (bid & 7);
    const int q = (bid >> 3) & 3;
    const int rt = p, ct = q;

    const char* Ab = (const char*)A + (size_t)rt * 131072;
    const char* Bb = (const char*)Bt + (size_t)ct * 131072;

    f32x4 acc[4][4] = {};

    const int o0  = tid * 16;
    const int r0s = o0 >> 6;
    const int c0s = o0 & 63;
    const int csw = c0s ^ (((r0s >> 1) & 3) << 4);

    auto stage = [&](char* buf, int k0b) {
        async16(Ab + (size_t)r0s * 1024 + k0b + csw,        buf + wid * 1024);
        async16(Ab + (size_t)(64 + r0s) * 1024 + k0b + csw, buf + 4096 + wid * 1024);
        async16(Bb + (size_t)r0s * 1024 + k0b + csw,        buf + 8192 + wid * 1024);
        async16(Bb + (size_t)(64 + r0s) * 1024 + k0b + csw, buf + 12288 + wid * 1024);
    };
    auto compute = [&](const char* buf) {
        s16x8 a[4], b[4];
        const int kx = kq * 16 ^ (((l15 >> 1) & 3) << 4);
        const int ar = wr * 64 + l15;
        const int br = wc * 64 + l15;
        #pragma unroll
        for (int m = 0; m < 4; ++m)
            a[m] = *(const s16x8*)(buf + (size_t)(ar + m * 16) * 64 + kx);
        #pragma unroll
        for (int n = 0; n < 4; ++n)
            b[n] = *(const s16x8*)(buf + 8192 + (size_t)(br + n * 16) * 64 + kx);
        #pragma unroll
        for (int m = 0; m < 4; ++m)
            #pragma unroll
            for (int n = 0; n < 4; ++n)
                acc[m][n] = __builtin_amdgcn_mfma_f32_16x16x32_bf16(a[m], b[n], acc[m][n], 0, 0, 0);
    };

    stage(lds[0], 0);
    stage(lds[1], 64);

    #pragma unroll 1
    for (int ks = 0; ks < 16; ks += 2) {
        const bool more = (ks + 2 < 16);
        asm volatile("s_waitcnt vmcnt(4)" ::: "memory");
        BAR;
        compute(lds[0]);
        BAR;
        if (more) stage(lds[0], (ks + 2) * 64);
        if (more) asm volatile("s_waitcnt vmcnt(4)" ::: "memory");
        else      asm volatile("s_waitcnt vmcnt(0)" ::: "memory");
        BAR;
        compute(lds[1]);
        BAR;
        if (more) stage(lds[1], (ks + 3) * 64);
    }

    const int cb = ct * 128 + wc * 64 + l15;
    const int rb = rt * 128 + wr * 64 + (kq << 2);
    #pragma unroll
    for (int m = 0; m < 4; ++m)
        #pragma unroll
        for (int n = 0; n < 4; ++n) {
            const int c = cb + n * 16;
            #pragma unroll
            for (int j = 0; j < 4; ++j) {
                const int r = rb + m * 16 + j;
                const size_t idx = (size_t)r * 512 + c;
                float v = acc[m][n][j] + bias[c];
                if (EPI == 3) out0[idx] = f2bf(fmaxf(v, 0.0f));
                else          outf[idx] = v;
            }
        }
}

// comb[b] = bf16( x0[b]/5000 + sum_c tp[b,c] + sum_c tz[b,c] )  — 16B/lane
__global__ __launch_bounds__(256) void reduce_both(
    const unsigned short* __restrict__ tp,
    const unsigned short* __restrict__ tz,
    const float* __restrict__ x0,
    unsigned short* __restrict__ comb)
{
    size_t idx = (size_t)blockIdx.x * 256 + threadIdx.x;   // ushort8 slot
    size_t b = idx >> 15;                                  // / (HI/8)
    size_t p = (idx & 32767) * 8;
    float4 xa = *(const float4*)&x0[(b * Cn) * HI + p];
    float4 xb = *(const float4*)&x0[(b * Cn) * HI + p + 4];
    float s[8] = { xa.x * SC, xa.y * SC, xa.z * SC, xa.w * SC,
                   xb.x * SC, xb.y * SC, xb.z * SC, xb.w * SC };
    #pragma unroll
    for (int c = 0; c < Cn; ++c) {
        size_t q = (b * Cn + c) * HI + p;
        u16x8 a = *(const u16x8*)&tp[q];
        u16x8 d = *(const u16x8*)&tz[q];
        #pragma unroll
        for (int j = 0; j < 8; ++j) s[j] += bf2f(a[j]) + bf2f(d[j]);
    }
    u16x8 o;
    #pragma unroll
    for (int j = 0; j < 8; ++j) o[j] = f2bf(s[j]);
    *(u16x8*)&comb[b * HI + p] = o;
}

// xst[bc][i][k] = bf16( x[bc][k][i] * act(mask[k][i]) / 5000 )
__global__ __launch_bounds__(256) void transpose_mask(
    const float* __restrict__ x, const float* __restrict__ mask,
    unsigned short* __restrict__ xst)
{
    __shared__ float t[64][65];
    const int bc = blockIdx.z;
    const int i0 = blockIdx.x * 64, k0 = blockIdx.y * 64;
    const int r16 = threadIdx.x >> 4;          // 0..15
    const int c4  = (threadIdx.x & 15) * 4;    // 0..60
    const float* xp = x + (size_t)bc * HI;
    #pragma unroll
    for (int ps = 0; ps < 4; ++ps) {
        const int kl = ps * 16 + r16;
        const size_t g = (size_t)(k0 + kl) * In + i0 + c4;
        float4 xv = *(const float4*)&xp[g];
        float4 mv = *(const float4*)&mask[g];
        t[kl][c4 + 0] = xv.x * (actf(mv.x) * SC);
        t[kl][c4 + 1] = xv.y * (actf(mv.y) * SC);
        t[kl][c4 + 2] = xv.z * (actf(mv.z) * SC);
        t[kl][c4 + 3] = xv.w * (actf(mv.w) * SC);
    }
    __syncthreads();
    unsigned short* op = xst + (size_t)bc * HI;
    #pragma unroll
    for (int ps = 0; ps < 4; ++ps) {
        const int il = ps * 16 + r16;
        ushort4 o;
        o.x = f2bf(t[c4 + 0][il]);
        o.y = f2bf(t[c4 + 1][il]);
        o.z = f2bf(t[c4 + 2][il]);
        o.w = f2bf(t[c4 + 3][il]);
        *(ushort4*)&op[(size_t)(i0 + il) * Hn + k0 + c4] = o;
    }
}

__global__ __launch_bounds__(256) void prep_wpe_bf(
    const float* __restrict__ Wp, const float* __restrict__ Wpd,
    unsigned short* __restrict__ o)
{
    int idx = blockIdx.x * 256 + threadIdx.x;
    int i = idx >> 9, j = idx & 511;
    o[idx] = f2bf(Wp[idx] + (i == j ? Wpd[i] : 0.0f));
}

// all four weight conversions in one launch (float4 in, ushort4 out)
__global__ __launch_bounds__(256) void conv_bf4(
    const float* __restrict__ s0, const float* __restrict__ s1,
    const float* __restrict__ s2, const float* __restrict__ s3,
    unsigned short* __restrict__ d0, unsigned short* __restrict__ d1,
    unsigned short* __restrict__ d2, unsigned short* __restrict__ d3)
{
    const int m = blockIdx.x >> 8;                       // 256 blocks/matrix
    const int idx = ((blockIdx.x & 255) * 256 + threadIdx.x);  // float4 idx
    const float* s = (m == 0) ? s0 : (m == 1) ? s1 : (m == 2) ? s2 : s3;
    unsigned short* d = (m == 0) ? d0 : (m == 1) ? d1 : (m == 2) ? d2 : d3;
    float4 v = ((const float4*)s)[idx];
    ushort4 o;
    o.x = f2bf(v.x); o.y = f2bf(v.y); o.z = f2bf(v.z); o.w = f2bf(v.w);
    ((ushort4*)d)[idx] = o;
}

__global__ __launch_bounds__(64) void rowsum(
    const float* __restrict__ W, float* __restrict__ zr)
{
    int h = blockIdx.x, l = threadIdx.x;
    float s = 0.0f;
    for (int k = l; k < Hn; k += 64) s += W[h * Hn + k];
    #pragma unroll
    for (int off = 32; off; off >>= 1) s += __shfl_down(s, off, 64);
    if (!l) zr[h] = s;
}

} // namespace

extern "C" void kernel_launch(void* const* d_in, const int* in_sizes, int n_in,
                              void* d_out, int out_size, void* d_ws, size_t ws_size,
                              hipStream_t stream)
{
    const float* input  = (const float*)d_in[0];
    const float* p_mask = (const float*)d_in[1];
    const float* Wp     = (const float*)d_in[2];
    const float* Wpd    = (const float*)d_in[3];
    const float* Wzp    = (const float*)d_in[4];
    const float* plw    = (const float*)d_in[5];
    const float* plb    = (const float*)d_in[6];
    const float* zlw    = (const float*)d_in[7];
    const float* zlb    = (const float*)d_in[8];
    const float* f1w    = (const float*)d_in[9];
    const float* f1b    = (const float*)d_in[10];
    const float* f2w    = (const float*)d_in[11];
    const float* f2b    = (const float*)d_in[12];

    constexpr size_t WB = 512 * 512 * 2;   // one bf16 weight matrix
    char* w = (char*)d_ws;
    auto alloc = [&](size_t bytes) { char* p = w; w += (bytes + 255) & ~255ull; return p; };

    unsigned short* Wpeb  = (unsigned short*)alloc(WB);
    unsigned short* plwb  = (unsigned short*)alloc(WB);
    unsigned short* zlwb  = (unsigned short*)alloc(WB);
    unsigned short* f1wb  = (unsigned short*)alloc(WB);
    unsigned short* f2wb  = (unsigned short*)alloc(WB);
    float*          zrw   = (float*)alloc(512 * 4);
    unsigned short* combb = (unsigned short*)alloc((size_t)Bn * HI * 2);
    unsigned short* out1  = (unsigned short*)alloc((size_t)Bn * HI * 2);

    size_t fixedB = (size_t)(w - (char*)d_ws);
    int chunk = 32;
    while (chunk > 1 &&
           fixedB + 4ull * (size_t)chunk * Cn * HI * 2 + 4096 > ws_size)
        chunk >>= 1;
    const size_t CB = (size_t)chunk * Cn * HI * 2;
    unsigned short* xst   = (unsigned short*)alloc(CB);   // reused for tz
    unsigned short* tpact = (unsigned short*)alloc(CB);
    unsigned short* tpb   = (unsigned short*)alloc(CB);
    unsigned short* tzin  = (unsigned short*)alloc(CB);
    unsigned short* tzb   = xst;

    prep_wpe_bf<<<512 * 512 / 256, 256, 0, stream>>>(Wp, Wpd, Wpeb);
    conv_bf4<<<1024, 256, 0, stream>>>(plw, zlw, f1w, f2w, plwb, zlwb, f1wb, f2wb);
    rowsum<<<512, 64, 0, stream>>>(Wzp, zrw);

    for (int b0 = 0; b0 < Bn; b0 += chunk) {
        const int nc = chunk * Cn;
        const float* inp_c = input + (size_t)b0 * Cn * HI;

        // xst = bf16(x^T * act(mask)/5000)
        transpose_mask<<<dim3(8, 8, nc), 256, 0, stream>>>(inp_c, p_mask, xst);
        // G1: tpact[z] = act(Wpe @ xst[z]^T)  — 8-phase 256², PCOL + TRI
        gemm256_8p<0, true, true><<<nc * 4, 512, 0, stream>>>(
            Wpeb, xst, nullptr, nullptr, tpact, nullptr, HI, HI);
        // G2: tp = act(tpact @ plw^T + plb); tzin = act(zrow*tp)
        gemm256_8p<1, false, false><<<nc * 4, 512, 0, stream>>>(
            tpact, plwb, plb, zrw, tpb, tzin, 0, 0);
        // G3: tz = act(tzin @ zlw^T + zlb)
        gemm256_8p<2, false, false><<<nc * 4, 512, 0, stream>>>(
            tzin, zlwb, zlb, nullptr, tzb, nullptr, 0, 0);
        // comb = x0/5000 + sum_c tp + sum_c tz
        reduce_both<<<chunk * 128, 256, 0, stream>>>(
            tpb, tzb, inp_c, combb + (size_t)b0 * HI);
    }

    // fc1: out1 = relu(combb @ f1w^T + f1b)
    mfma_gemm128<3><<<512, 256, 0, stream>>>(combb, f1wb, f1b, out1, nullptr);
    // fc2: out = out1 @ f2w^T + f2b   (fp32)
    mfma_gemm128<4><<<512, 256, 0, stream>>>(out1, f2wb, f2b, nullptr, (float*)d_out);
}